// Round 7
// baseline (333.398 us; speedup 1.0000x reference)
//
#include <hip/hip_runtime.h>
#include <hip/hip_bf16.h>

namespace {

constexpr int B = 2;
constexpr int N = 40000;
constexpr int E = 400000;
constexpr int R = 64;
constexpr int D = 64;
constexpr int L = 6;
constexpr float EPS = 1e-5f;
constexpr int NB = (N + 255) / 256;   // 157 node-grid blocks
constexpr int EB = (E + 255) / 256;   // 1563 edge-grid blocks

typedef _Float16 v8h __attribute__((ext_vector_type(8)));
typedef _Float16 v2h __attribute__((ext_vector_type(2)));
typedef float    v4f __attribute__((ext_vector_type(4)));

__device__ __forceinline__ unsigned int pack_h2(float a, float b) {
  v2h p; p.x = (_Float16)a; p.y = (_Float16)b;
  return __builtin_bit_cast(unsigned int, p);
}
__device__ __forceinline__ float2 unpack_h2(unsigned int u) {
  v2h p = __builtin_bit_cast(v2h, u);
  return make_float2((float)p.x, (float)p.y);
}

// Batch-interleaved packed element = (batch0, batch1) f16 in one dword.

// ---- relation projection MLP for all layers (+ last block does init) ----
__global__ __launch_bounds__(64) void k_rel(
    const float* __restrict__ rel_reps,
    const float* __restrict__ pw1, const float* __restrict__ pb1,
    const float* __restrict__ pw2, const float* __restrict__ pb2,
    float* __restrict__ rel_f,
    const int* __restrict__ h_index, const int* __restrict__ r_index,
    unsigned int* __restrict__ xb,
    _Float16* __restrict__ xrow0, _Float16* __restrict__ xrow1,
    float* __restrict__ query_f, _Float16* __restrict__ qh) {
  __shared__ float row[D];
  __shared__ float row2[D];
  int idx = blockIdx.x;             // [0, L*B*R] — last block = init
  int d = threadIdx.x;
  if (idx == L * B * R) {           // ---- init block ----
    int h0 = h_index[0], h1 = h_index[1];
    float q0 = rel_reps[r_index[0] * D + d];
    float q1 = rel_reps[(R + r_index[1]) * D + d];
    query_f[d * 2] = q0; query_f[d * 2 + 1] = q1;
    qh[d]     = (_Float16)q0;
    qh[D + d] = (_Float16)q1;
    if (h0 == h1) {
      xb[(size_t)h0 * D + d] = pack_h2(q0, q1);
    } else {
      xb[(size_t)h0 * D + d] = pack_h2(q0, 0.f);
      xb[(size_t)h1 * D + d] = pack_h2(0.f, q1);
    }
    xrow0[(size_t)h0 * 2 * D + d] = (_Float16)q0;   // x-half of A rows
    xrow1[(size_t)h1 * 2 * D + d] = (_Float16)q1;
    return;
  }
  int l = idx / (B * R);
  int br = idx - l * (B * R);       // b*R + r
  int b = br / R, r = br - b * R;
  row[d] = rel_reps[(size_t)br * D + d];
  __syncthreads();
  const float* w1 = pw1 + (size_t)l * D * D;
  float acc = pb1[l * D + d];
  for (int k = 0; k < D; ++k) acc = fmaf(row[k], w1[k * D + d], acc);
  row2[d] = fmaxf(acc, 0.f);
  __syncthreads();
  const float* w2 = pw2 + (size_t)l * D * D;
  float acc2 = pb2[l * D + d];
  for (int k = 0; k < D; ++k) acc2 = fmaf(row2[k], w2[k * D + d], acc2);
  rel_f[(((size_t)l * R + r) * D + d) * 2 + b] = acc2;
}

// ---- merged pack kernel: rel (96 blocks) | lin_w (24) | mlp_w (8) ----
__global__ __launch_bounds__(256) void k_pack(
    const float2* __restrict__ rel2, unsigned int* __restrict__ rel_pk,
    const float* __restrict__ lin_w, unsigned short* __restrict__ Wf,
    const float* __restrict__ mlp_w, unsigned short* __restrict__ Wm) {
  int blk = blockIdx.x;
  int tid = threadIdx.x;
  if (blk < 96) {                    // rel: L*R*D = 24576 dwords
    int i = blk * 256 + tid;
    float2 v = rel2[i];
    rel_pk[i] = pack_h2(v.x, v.y);
  } else if (blk < 120) {            // lin_w: L*16 = 96 frag-groups, 4/block
    int idx = (blk - 96) * 4 + (tid >> 6);
    int lane = tid & 63;
    int l = idx >> 4, ct = (idx >> 2) & 3, ks = idx & 3;
    int n = ct * 16 + (lane & 15);
    #pragma unroll
    for (int j = 0; j < 8; ++j) {
      int k = ks * 32 + (lane >> 4) * 8 + j;
      _Float16 v = (_Float16)lin_w[(size_t)l * 2 * D * D + (size_t)k * D + n];
      Wf[(size_t)l * 8192 + ((size_t)((ct * 4 + ks) * 64) + lane) * 8 + j] =
          __builtin_bit_cast(unsigned short, v);
    }
  } else {                           // mlp_w: 32 frag-groups, 4/block
    int idx = (blk - 120) * 4 + (tid >> 6);
    int lane = tid & 63;
    int ct = idx >> 2, ks = idx & 3;
    int n = ct * 16 + (lane & 15);
    #pragma unroll
    for (int j = 0; j < 8; ++j) {
      int k = ks * 32 + (lane >> 4) * 8 + j;
      _Float16 v = (_Float16)mlp_w[(size_t)k * 2 * D + n];
      Wm[((size_t)idx * 64 + lane) * 8 + j] = __builtin_bit_cast(unsigned short, v);
    }
  }
}

// ---- CSR build ----
__global__ __launch_bounds__(256) void k_hist(const int* __restrict__ dst,
                                              int* __restrict__ cnt) {
  int e = blockIdx.x * 256 + threadIdx.x;
  if (e < E) atomicAdd(&cnt[dst[e]], 1);
}

__global__ __launch_bounds__(256) void k_scan1(const int* __restrict__ cnt,
                                               int* __restrict__ row_ptr,
                                               int* __restrict__ bsum) {
  __shared__ int s[256];
  int t = threadIdx.x;
  int i = blockIdx.x * 256 + t;
  int v = (i < N) ? cnt[i] : 0;
  s[t] = v;
  __syncthreads();
  #pragma unroll
  for (int off = 1; off < 256; off <<= 1) {   // Hillis-Steele inclusive
    int u = (t >= off) ? s[t - off] : 0;
    __syncthreads();
    s[t] += u;
    __syncthreads();
  }
  if (i < N) row_ptr[i] = s[t] - v;           // exclusive-in-block
  if (t == 255) bsum[blockIdx.x] = s[255];
}

// scan3: add prefix of block sums (block-reduced in LDS) + init cursor.
__global__ __launch_bounds__(256) void k_scan3(int* __restrict__ row_ptr,
                                               const int* __restrict__ bsum,
                                               int* __restrict__ cursor) {
  __shared__ int red[256];
  int t = threadIdx.x;
  int v = (t < (int)blockIdx.x) ? bsum[t] : 0;   // blockIdx.x <= 156 < 256
  red[t] = v;
  __syncthreads();
  #pragma unroll
  for (int off = 128; off > 0; off >>= 1) {
    if (t < off) red[t] += red[t + off];
    __syncthreads();
  }
  int offv = red[0];
  int i = blockIdx.x * 256 + t;
  if (i < N) {
    int r = row_ptr[i] + offv;
    row_ptr[i] = r;
    cursor[i] = r;
  }
  if (i == N - 1) row_ptr[N] = E;
}

__global__ __launch_bounds__(256) void k_fill(const int* __restrict__ src,
                                              const int* __restrict__ dst,
                                              const int* __restrict__ etype,
                                              int* __restrict__ cursor,
                                              unsigned int* __restrict__ es) {
  int e = blockIdx.x * 256 + threadIdx.x;
  if (e < E) {
    int p = atomicAdd(&cursor[dst[e]], 1);
    es[p] = (unsigned int)src[e] | ((unsigned int)etype[e] << 16);  // src < 65536
  }
}

// ---- gather: FOUR nodes per wave (quarter-wave each, uint4 16B loads/lane).
// R3 base (unroll-4, occ 6) + PREDICATED loads: done quarters skip their
// load slots entirely (exec-masked) instead of re-loading edge dc-1.
// Removes ~35% wasted VMEM work (Poisson-10 imbalance across quarters).
// deg<=16 fast path, overflow loop for deg>16 (~2.7%). Zero LDS.
__global__ __launch_bounds__(256, 6) void k_gather(
    const unsigned int* __restrict__ xb,
    _Float16* __restrict__ xrow0, _Float16* __restrict__ xrow1,
    const unsigned int* __restrict__ rel_pk,     // [R*D] this layer, packed
    const int* __restrict__ row_ptr, const unsigned int* __restrict__ es,
    const float2* __restrict__ q2, const int* __restrict__ h_index, int first) {
  int tid = threadIdx.x;
  int lane = tid & 63;
  int q = lane >> 4;                 // quarter: which of 4 nodes
  int lq = lane & 15;                // lane within quarter (dims 4lq..4lq+3)
  int w = (blockIdx.x * 256 + tid) >> 6;       // wave id in [0, N/4)
  int n = w * 4 + q;                 // node for this quarter
  int h0 = h_index[0], h1 = h_index[1];
  int rp = 0;
  if (lane < 5) rp = row_ptr[4 * w + lane];    // row_ptr[4w .. 4w+4]
  int rs = __shfl(rp, q);
  int re = __shfl(rp, q + 1);
  int deg = re - rs;
  int dc = min(deg, 16);
  unsigned int esv = 0;
  if (lq < dc) esv = es[rs + lq];              // quarter's edge list, one load
  float ax[4] = {0.f, 0.f, 0.f, 0.f};          // batch0, dims 4lq+0..3
  float ay[4] = {0.f, 0.f, 0.f, 0.f};          // batch1
  if (first) {
    // layer 0: x nonzero only at h0 (batch0) / h1 (batch1); loads only on match
    for (int j = 0; j < dc; ++j) {
      unsigned int pk = __shfl(esv, (q << 4) | j);
      int s = (int)(pk & 0xffffu), et = (int)(pk >> 16);
      if (s == h0 || s == h1) {
        uint4 xv = *(const uint4*)&xb[(size_t)s * D + 4 * lq];
        uint4 rv = *(const uint4*)&rel_pk[et * D + 4 * lq];
        float2 x0 = unpack_h2(xv.x), x1 = unpack_h2(xv.y),
               x2 = unpack_h2(xv.z), x3 = unpack_h2(xv.w);
        float2 r0 = unpack_h2(rv.x), r1 = unpack_h2(rv.y),
               r2 = unpack_h2(rv.z), r3 = unpack_h2(rv.w);
        if (s == h0) {
          ax[0] = fmaf(x0.x, r0.x, ax[0]); ax[1] = fmaf(x1.x, r1.x, ax[1]);
          ax[2] = fmaf(x2.x, r2.x, ax[2]); ax[3] = fmaf(x3.x, r3.x, ax[3]);
        }
        if (s == h1) {
          ay[0] = fmaf(x0.y, r0.y, ay[0]); ay[1] = fmaf(x1.y, r1.y, ay[1]);
          ay[2] = fmaf(x2.y, r2.y, ay[2]); ay[3] = fmaf(x3.y, r3.y, ay[3]);
        }
      }
    }
    for (int j = rs + 16; j < re; ++j) {       // overflow (rare)
      unsigned int pk = es[j];
      int s = (int)(pk & 0xffffu), et = (int)(pk >> 16);
      if (s == h0 || s == h1) {
        uint4 xv = *(const uint4*)&xb[(size_t)s * D + 4 * lq];
        uint4 rv = *(const uint4*)&rel_pk[et * D + 4 * lq];
        float2 x0 = unpack_h2(xv.x), x1 = unpack_h2(xv.y),
               x2 = unpack_h2(xv.z), x3 = unpack_h2(xv.w);
        float2 r0 = unpack_h2(rv.x), r1 = unpack_h2(rv.y),
               r2 = unpack_h2(rv.z), r3 = unpack_h2(rv.w);
        if (s == h0) {
          ax[0] = fmaf(x0.x, r0.x, ax[0]); ax[1] = fmaf(x1.x, r1.x, ax[1]);
          ax[2] = fmaf(x2.x, r2.x, ax[2]); ax[3] = fmaf(x3.x, r3.x, ax[3]);
        }
        if (s == h1) {
          ay[0] = fmaf(x0.y, r0.y, ay[0]); ay[1] = fmaf(x1.y, r1.y, ay[1]);
          ay[2] = fmaf(x2.y, r2.y, ay[2]); ay[3] = fmaf(x3.y, r3.y, ay[3]);
        }
      }
    }
  } else {
    int rounds = (dc + 3) >> 2;
    int r0q = __shfl(rounds, 0), r1q = __shfl(rounds, 16);
    int r2q = __shfl(rounds, 32), r3q = __shfl(rounds, 48);
    int maxr = max(max(r0q, r1q), max(r2q, r3q));   // wave-uniform bound
    for (int jr = 0; jr < maxr; ++jr) {
      int j = jr * 4;
      unsigned int pk[4];
      uint4 xv[4], rv[4];
      #pragma unroll
      for (int u = 0; u < 4; ++u) {
        int iu = max(min(j + u, dc - 1), 0);   // clamped (shfl must stay wave-wide)
        pk[u] = __shfl(esv, (q << 4) | iu);
      }
      #pragma unroll
      for (int u = 0; u < 4; ++u) {
        if (j + u < dc) {                      // predicated: done quarters skip
          xv[u] = *(const uint4*)&xb[(size_t)(pk[u] & 0xffffu) * D + 4 * lq];
          rv[u] = *(const uint4*)&rel_pk[(pk[u] >> 16) * D + 4 * lq];
        }
      }
      #pragma unroll
      for (int u = 0; u < 4; ++u) {
        if (j + u < dc) {
          float2 x0 = unpack_h2(xv[u].x), x1 = unpack_h2(xv[u].y),
                 x2 = unpack_h2(xv[u].z), x3 = unpack_h2(xv[u].w);
          float2 r0 = unpack_h2(rv[u].x), r1 = unpack_h2(rv[u].y),
                 r2 = unpack_h2(rv[u].z), r3 = unpack_h2(rv[u].w);
          ax[0] = fmaf(x0.x, r0.x, ax[0]); ay[0] = fmaf(x0.y, r0.y, ay[0]);
          ax[1] = fmaf(x1.x, r1.x, ax[1]); ay[1] = fmaf(x1.y, r1.y, ay[1]);
          ax[2] = fmaf(x2.x, r2.x, ax[2]); ay[2] = fmaf(x2.y, r2.y, ay[2]);
          ax[3] = fmaf(x3.x, r3.x, ax[3]); ay[3] = fmaf(x3.y, r3.y, ay[3]);
        }
      }
    }
    for (int j = rs + 16; j < re; ++j) {       // overflow (rare)
      unsigned int pk = es[j];
      uint4 xv = *(const uint4*)&xb[(size_t)(pk & 0xffffu) * D + 4 * lq];
      uint4 rv = *(const uint4*)&rel_pk[(pk >> 16) * D + 4 * lq];
      float2 x0 = unpack_h2(xv.x), x1 = unpack_h2(xv.y),
             x2 = unpack_h2(xv.z), x3 = unpack_h2(xv.w);
      float2 r0 = unpack_h2(rv.x), r1 = unpack_h2(rv.y),
             r2 = unpack_h2(rv.z), r3 = unpack_h2(rv.w);
      ax[0] = fmaf(x0.x, r0.x, ax[0]); ay[0] = fmaf(x0.y, r0.y, ay[0]);
      ax[1] = fmaf(x1.x, r1.x, ax[1]); ay[1] = fmaf(x1.y, r1.y, ay[1]);
      ax[2] = fmaf(x2.x, r2.x, ax[2]); ay[2] = fmaf(x2.y, r2.y, ay[2]);
      ax[3] = fmaf(x3.x, r3.x, ax[3]); ay[3] = fmaf(x3.y, r3.y, ay[3]);
    }
  }
  // + boundary (fp32): q2[d] = (batch0 val, batch1 val) of dim d
  if (n == h0) {
    const float4* qp = (const float4*)&q2[4 * lq];   // q2[4lq], q2[4lq+1]
    float4 qa = qp[0], qb = qp[1];
    ax[0] += qa.x; ax[1] += qa.z; ax[2] += qb.x; ax[3] += qb.z;
  }
  if (n == h1) {
    const float4* qp = (const float4*)&q2[4 * lq];
    float4 qa = qp[0], qb = qp[1];
    ay[0] += qa.y; ay[1] += qa.w; ay[2] += qb.y; ay[3] += qb.w;
  }
  uint2 st0, st1;
  st0.x = pack_h2(ax[0], ax[1]); st0.y = pack_h2(ax[2], ax[3]);
  st1.x = pack_h2(ay[0], ay[1]); st1.y = pack_h2(ay[2], ay[3]);
  *(uint2*)&xrow0[(size_t)n * 2 * D + D + 4 * lq] = st0;   // agg-half of A rows
  *(uint2*)&xrow1[(size_t)n * 2 * D + D + 4 * lq] = st1;
}

// ---- MFMA linear + LN + relu + shortcut ----
// One wave per 16-node tile, both batches. Zero LDS. Grid 2500 x 64.
// Residual read from xb (f16) — no fp32 x buffer.
__global__ __launch_bounds__(64) void k_linear(
    unsigned int* __restrict__ xb,
    _Float16* __restrict__ xrow0, _Float16* __restrict__ xrow1,
    const unsigned short* __restrict__ Wf,
    const float* __restrict__ lin_b, const float* __restrict__ ln_g,
    const float* __restrict__ ln_b, int layer) {
  int lane = threadIdx.x;
  int nb = blockIdx.x * 16;
  int c = lane & 15, rg = lane >> 4;
  // B-fragments (16 x 16 B, L2-hot)
  const v8h* wf = (const v8h*)(Wf + (size_t)layer * 8192);
  v8h Bf[4][4];
  #pragma unroll
  for (int ct = 0; ct < 4; ++ct)
    #pragma unroll
    for (int ks = 0; ks < 4; ++ks)
      Bf[ct][ks] = wf[(ct * 4 + ks) * 64 + lane];
  v4f acc0[4], acc1[4];
  #pragma unroll
  for (int ct = 0; ct < 4; ++ct) {
    acc0[ct] = (v4f){0.f, 0.f, 0.f, 0.f};
    acc1[ct] = (v4f){0.f, 0.f, 0.f, 0.f};
  }
  // K-loop: 4 k-steps x (2 A-loads + 8 MFMA)
  #pragma unroll
  for (int ks = 0; ks < 4; ++ks) {
    size_t aoff = (size_t)(nb + c) * 2 * D + ks * 32 + rg * 8;
    v8h A0 = *(const v8h*)(xrow0 + aoff);
    v8h A1 = *(const v8h*)(xrow1 + aoff);
    #pragma unroll
    for (int ct = 0; ct < 4; ++ct) {
      acc0[ct] = __builtin_amdgcn_mfma_f32_16x16x32_f16(A0, Bf[ct][ks], acc0[ct], 0, 0, 0);
      acc1[ct] = __builtin_amdgcn_mfma_f32_16x16x32_f16(A1, Bf[ct][ks], acc1[ct], 0, 0, 0);
    }
  }
  // epilogue: +bias, LN over 64 outs (16-lane col-group x 4 ct), relu, +x
  float bias4[4], g4[4], be4[4];
  #pragma unroll
  for (int ct = 0; ct < 4; ++ct) {
    int d = ct * 16 + c;
    bias4[ct] = lin_b[layer * D + d];
    g4[ct]    = ln_g[layer * D + d];
    be4[ct]   = ln_b[layer * D + d];
  }
  #pragma unroll
  for (int j = 0; j < 4; ++j) {
    int node = nb + rg * 4 + j;
    float v0[4], v1[4];
    float s10 = 0.f, s20 = 0.f, s11 = 0.f, s21 = 0.f;
    #pragma unroll
    for (int ct = 0; ct < 4; ++ct) {
      v0[ct] = acc0[ct][j] + bias4[ct];
      v1[ct] = acc1[ct][j] + bias4[ct];
      s10 += v0[ct]; s20 += v0[ct] * v0[ct];
      s11 += v1[ct]; s21 += v1[ct] * v1[ct];
    }
    #pragma unroll
    for (int mk = 1; mk < 16; mk <<= 1) {   // reduce over the 16-lane col group
      s10 += __shfl_xor(s10, mk); s20 += __shfl_xor(s20, mk);
      s11 += __shfl_xor(s11, mk); s21 += __shfl_xor(s21, mk);
    }
    float mu0 = s10 * (1.f / D), var0 = s20 * (1.f / D) - mu0 * mu0;
    float mu1 = s11 * (1.f / D), var1 = s21 * (1.f / D) - mu1 * mu1;
    float rs0 = rsqrtf(var0 + EPS), rs1 = rsqrtf(var1 + EPS);
    #pragma unroll
    for (int ct = 0; ct < 4; ++ct) {
      int d = ct * 16 + c;
      float o0 = fmaxf((v0[ct] - mu0) * rs0 * g4[ct] + be4[ct], 0.f);
      float o1 = fmaxf((v1[ct] - mu1) * rs1 * g4[ct] + be4[ct], 0.f);
      float2 xv = unpack_h2(xb[(size_t)node * D + d]);    // f16 residual
      float r0 = o0 + xv.x, r1 = o1 + xv.y;
      xb[(size_t)node * D + d] = pack_h2(r0, r1);          // for gather / residual
      xrow0[(size_t)node * 2 * D + d] = (_Float16)r0;      // x-half for next linear/mlp
      xrow1[(size_t)node * 2 * D + d] = (_Float16)r1;
    }
  }
}

// ---- MFMA final MLP: relu([x, query] @ mlp_w + mlp_b) -> fp32 out ----
__global__ __launch_bounds__(64) void k_mlp(
    const _Float16* __restrict__ xrow0, const _Float16* __restrict__ xrow1,
    const _Float16* __restrict__ qh,            // [2][64] f16
    const unsigned short* __restrict__ Wm,      // 32 fragments
    const float* __restrict__ mlp_b,
    float* __restrict__ outf) {
  int lane = threadIdx.x;
  int nb = blockIdx.x * 16;
  int c = lane & 15, rg = lane >> 4;
  const v8h* wm = (const v8h*)Wm;
  v4f acc0[8], acc1[8];
  #pragma unroll
  for (int ct = 0; ct < 8; ++ct) {
    acc0[ct] = (v4f){0.f, 0.f, 0.f, 0.f};
    acc1[ct] = (v4f){0.f, 0.f, 0.f, 0.f};
  }
  #pragma unroll
  for (int ks = 0; ks < 4; ++ks) {
    v8h A0, A1;
    if (ks < 2) {                       // x half: k = ks*32 + rg*8 + j in [0,64)
      size_t aoff = (size_t)(nb + c) * 2 * D + ks * 32 + rg * 8;
      A0 = *(const v8h*)(xrow0 + aoff);
      A1 = *(const v8h*)(xrow1 + aoff);
    } else {                            // query half: node-invariant
      int qoff = (ks - 2) * 32 + rg * 8;
      A0 = *(const v8h*)(qh + qoff);
      A1 = *(const v8h*)(qh + D + qoff);
    }
    #pragma unroll
    for (int ct = 0; ct < 8; ++ct) {
      v8h Bv = wm[(ct * 4 + ks) * 64 + lane];
      acc0[ct] = __builtin_amdgcn_mfma_f32_16x16x32_f16(A0, Bv, acc0[ct], 0, 0, 0);
      acc1[ct] = __builtin_amdgcn_mfma_f32_16x16x32_f16(A1, Bv, acc1[ct], 0, 0, 0);
    }
  }
  // epilogue: +bias, relu, store. out flat = [2][N][128] fp32.
  #pragma unroll
  for (int ct = 0; ct < 8; ++ct) {
    int d = ct * 16 + c;
    float bias = mlp_b[d];
    #pragma unroll
    for (int j = 0; j < 4; ++j) {
      int node = nb + rg * 4 + j;
      outf[(size_t)node * 2 * D + d]       = fmaxf(acc0[ct][j] + bias, 0.f);
      outf[((size_t)N + node) * 2 * D + d] = fmaxf(acc1[ct][j] + bias, 0.f);
    }
  }
}

}  // namespace

extern "C" void kernel_launch(void* const* d_in, const int* in_sizes, int n_in,
                              void* d_out, int out_size, void* d_ws, size_t ws_size,
                              hipStream_t stream) {
  const float* rel_reps = (const float*)d_in[0];
  const int* h_index    = (const int*)d_in[1];
  const int* r_index    = (const int*)d_in[2];
  const int* edge_index = (const int*)d_in[3];
  const int* edge_type  = (const int*)d_in[4];
  const float* proj_w1  = (const float*)d_in[5];
  const float* proj_b1  = (const float*)d_in[6];
  const float* proj_w2  = (const float*)d_in[7];
  const float* proj_b2  = (const float*)d_in[8];
  const float* lin_w    = (const float*)d_in[9];
  const float* lin_b    = (const float*)d_in[10];
  const float* ln_g     = (const float*)d_in[11];
  const float* ln_b     = (const float*)d_in[12];
  const float* mlp_w    = (const float*)d_in[13];
  const float* mlp_b    = (const float*)d_in[14];

  // workspace: xb | xrow0 | xrow1 (one contiguous zero region, 30.7 MB) |
  //            rel_pk | Wf | Wm | qh | rel_all | query | cnt | row_ptr |
  //            cursor | es | bsum    (big 16B-aligned arrays first)
  unsigned int* xb = (unsigned int*)d_ws;                  // N*D
  _Float16* xrow0 = (_Float16*)(xb + (size_t)N * D);       // N*128
  _Float16* xrow1 = xrow0 + (size_t)N * 2 * D;             // N*128
  unsigned int* rel_pk = (unsigned int*)(xrow1 + (size_t)N * 2 * D);  // L*R*D
  unsigned short* Wf = (unsigned short*)(rel_pk + (size_t)L * R * D); // L*8192
  unsigned short* Wm = Wf + (size_t)L * 8192;              // 16384
  _Float16* qh = (_Float16*)(Wm + 16384);                  // 128
  float* rel_all = (float*)(qh + 128);                     // 2*L*R*D
  float* query   = rel_all + (size_t)2 * L * R * D;        // 2*D
  int*   cnt     = (int*)(query + 2 * D);
  int*   row_ptr = cnt + N;
  int*   cursor  = row_ptr + (N + 1);
  unsigned int* es = (unsigned int*)(cursor + N);
  int*   bsum    = (int*)(es + E);

  const int* srcp = edge_index;
  const int* dstp = edge_index + E;

  // one memset covers xb + xrow0 + xrow1 (contiguous)
  hipMemsetAsync(xb, 0, (size_t)N * D * 4 + (size_t)N * 2 * D * 2 * 2, stream);
  hipMemsetAsync(cnt, 0, N * sizeof(int), stream);
  k_rel<<<L * B * R + 1, 64, 0, stream>>>(rel_reps, proj_w1, proj_b1, proj_w2, proj_b2,
                                          rel_all, h_index, r_index,
                                          xb, xrow0, xrow1, query, qh);
  k_pack<<<128, 256, 0, stream>>>((const float2*)rel_all, rel_pk, lin_w, Wf, mlp_w, Wm);
  k_hist<<<EB, 256, 0, stream>>>(dstp, cnt);
  k_scan1<<<NB, 256, 0, stream>>>(cnt, row_ptr, bsum);
  k_scan3<<<NB, 256, 0, stream>>>(row_ptr, bsum, cursor);
  k_fill<<<EB, 256, 0, stream>>>(srcp, dstp, edge_type, cursor, es);

  for (int l = 0; l < L; ++l) {
    k_gather<<<N / 16, 256, 0, stream>>>(xb, xrow0, xrow1,
                                         rel_pk + (size_t)l * R * D,
                                         row_ptr, es, (const float2*)query, h_index,
                                         (l == 0) ? 1 : 0);
    k_linear<<<N / 16, 64, 0, stream>>>(xb, xrow0, xrow1,
                                        Wf, lin_b, ln_g, ln_b, l);
  }
  k_mlp<<<N / 16, 64, 0, stream>>>(xrow0, xrow1, qh, Wm, mlp_b, (float*)d_out);
}

// Round 8
// 326.943 us; speedup vs baseline: 1.0197x; 1.0197x over previous
//
#include <hip/hip_runtime.h>
#include <hip/hip_bf16.h>

namespace {

constexpr int B = 2;
constexpr int N = 40000;
constexpr int E = 400000;
constexpr int R = 64;
constexpr int D = 64;
constexpr int L = 6;
constexpr float EPS = 1e-5f;
constexpr int NB = (N + 255) / 256;   // 157 node-grid blocks
constexpr int EB = (E + 255) / 256;   // 1563 edge-grid blocks

typedef _Float16 v8h __attribute__((ext_vector_type(8)));
typedef _Float16 v2h __attribute__((ext_vector_type(2)));
typedef float    v4f __attribute__((ext_vector_type(4)));

__device__ __forceinline__ unsigned int pack_h2(float a, float b) {
  v2h p; p.x = (_Float16)a; p.y = (_Float16)b;
  return __builtin_bit_cast(unsigned int, p);
}
__device__ __forceinline__ float2 unpack_h2(unsigned int u) {
  v2h p = __builtin_bit_cast(v2h, u);
  return make_float2((float)p.x, (float)p.y);
}
__device__ __forceinline__ v8h zero8() {
  uint4 z; z.x = 0u; z.y = 0u; z.z = 0u; z.w = 0u;
  return __builtin_bit_cast(v8h, z);
}

// Batch-interleaved packed element = (batch0, batch1) f16 in one dword.

// ---- relation projection MLP for all layers (+ last block does init) ----
__global__ __launch_bounds__(64) void k_rel(
    const float* __restrict__ rel_reps,
    const float* __restrict__ pw1, const float* __restrict__ pb1,
    const float* __restrict__ pw2, const float* __restrict__ pb2,
    float* __restrict__ rel_f,
    const int* __restrict__ h_index, const int* __restrict__ r_index,
    unsigned int* __restrict__ xb,
    float* __restrict__ query_f, _Float16* __restrict__ qh) {
  __shared__ float row[D];
  __shared__ float row2[D];
  int idx = blockIdx.x;             // [0, L*B*R] — last block = init
  int d = threadIdx.x;
  if (idx == L * B * R) {           // ---- init block ----
    int h0 = h_index[0], h1 = h_index[1];
    float q0 = rel_reps[r_index[0] * D + d];
    float q1 = rel_reps[(R + r_index[1]) * D + d];
    query_f[d * 2] = q0; query_f[d * 2 + 1] = q1;
    qh[d]     = (_Float16)q0;
    qh[D + d] = (_Float16)q1;
    if (h0 == h1) {
      xb[(size_t)h0 * D + d] = pack_h2(q0, q1);
    } else {
      xb[(size_t)h0 * D + d] = pack_h2(q0, 0.f);
      xb[(size_t)h1 * D + d] = pack_h2(0.f, q1);
    }
    return;
  }
  int l = idx / (B * R);
  int br = idx - l * (B * R);       // b*R + r
  int b = br / R, r = br - b * R;
  row[d] = rel_reps[(size_t)br * D + d];
  __syncthreads();
  const float* w1 = pw1 + (size_t)l * D * D;
  float acc = pb1[l * D + d];
  for (int k = 0; k < D; ++k) acc = fmaf(row[k], w1[k * D + d], acc);
  row2[d] = fmaxf(acc, 0.f);
  __syncthreads();
  const float* w2 = pw2 + (size_t)l * D * D;
  float acc2 = pb2[l * D + d];
  for (int k = 0; k < D; ++k) acc2 = fmaf(row2[k], w2[k * D + d], acc2);
  rel_f[(((size_t)l * R + r) * D + d) * 2 + b] = acc2;
}

// ---- merged pack kernel: rel (96 blocks) | lin_w (24) | mlp_w (8) ----
__global__ __launch_bounds__(256) void k_pack(
    const float2* __restrict__ rel2, unsigned int* __restrict__ rel_pk,
    const float* __restrict__ lin_w, unsigned short* __restrict__ Wf,
    const float* __restrict__ mlp_w, unsigned short* __restrict__ Wm) {
  int blk = blockIdx.x;
  int tid = threadIdx.x;
  if (blk < 96) {                    // rel: L*R*D = 24576 dwords
    int i = blk * 256 + tid;
    float2 v = rel2[i];
    rel_pk[i] = pack_h2(v.x, v.y);
  } else if (blk < 120) {            // lin_w: L*16 = 96 frag-groups, 4/block
    int idx = (blk - 96) * 4 + (tid >> 6);
    int lane = tid & 63;
    int l = idx >> 4, ct = (idx >> 2) & 3, ks = idx & 3;
    int n = ct * 16 + (lane & 15);
    #pragma unroll
    for (int j = 0; j < 8; ++j) {
      int k = ks * 32 + (lane >> 4) * 8 + j;
      _Float16 v = (_Float16)lin_w[(size_t)l * 2 * D * D + (size_t)k * D + n];
      Wf[(size_t)l * 8192 + ((size_t)((ct * 4 + ks) * 64) + lane) * 8 + j] =
          __builtin_bit_cast(unsigned short, v);
    }
  } else {                           // mlp_w: 32 frag-groups, 4/block
    int idx = (blk - 120) * 4 + (tid >> 6);
    int lane = tid & 63;
    int ct = idx >> 2, ks = idx & 3;
    int n = ct * 16 + (lane & 15);
    #pragma unroll
    for (int j = 0; j < 8; ++j) {
      int k = ks * 32 + (lane >> 4) * 8 + j;
      _Float16 v = (_Float16)mlp_w[(size_t)k * 2 * D + n];
      Wm[((size_t)idx * 64 + lane) * 8 + j] = __builtin_bit_cast(unsigned short, v);
    }
  }
}

// ---- CSR build ----
__global__ __launch_bounds__(256) void k_hist(const int* __restrict__ dst,
                                              int* __restrict__ cnt) {
  int e = blockIdx.x * 256 + threadIdx.x;
  if (e < E) atomicAdd(&cnt[dst[e]], 1);
}

__global__ __launch_bounds__(256) void k_scan1(const int* __restrict__ cnt,
                                               int* __restrict__ row_ptr,
                                               int* __restrict__ bsum) {
  __shared__ int s[256];
  int t = threadIdx.x;
  int i = blockIdx.x * 256 + t;
  int v = (i < N) ? cnt[i] : 0;
  s[t] = v;
  __syncthreads();
  #pragma unroll
  for (int off = 1; off < 256; off <<= 1) {   // Hillis-Steele inclusive
    int u = (t >= off) ? s[t - off] : 0;
    __syncthreads();
    s[t] += u;
    __syncthreads();
  }
  if (i < N) row_ptr[i] = s[t] - v;           // exclusive-in-block
  if (t == 255) bsum[blockIdx.x] = s[255];
}

// scan3: add prefix of block sums (block-reduced in LDS) + init cursor.
__global__ __launch_bounds__(256) void k_scan3(int* __restrict__ row_ptr,
                                               const int* __restrict__ bsum,
                                               int* __restrict__ cursor) {
  __shared__ int red[256];
  int t = threadIdx.x;
  int v = (t < (int)blockIdx.x) ? bsum[t] : 0;   // blockIdx.x <= 156 < 256
  red[t] = v;
  __syncthreads();
  #pragma unroll
  for (int off = 128; off > 0; off >>= 1) {
    if (t < off) red[t] += red[t + off];
    __syncthreads();
  }
  int offv = red[0];
  int i = blockIdx.x * 256 + t;
  if (i < N) {
    int r = row_ptr[i] + offv;
    row_ptr[i] = r;
    cursor[i] = r;
  }
  if (i == N - 1) row_ptr[N] = E;
}

__global__ __launch_bounds__(256) void k_fill(const int* __restrict__ src,
                                              const int* __restrict__ dst,
                                              const int* __restrict__ etype,
                                              int* __restrict__ cursor,
                                              unsigned int* __restrict__ es) {
  int e = blockIdx.x * 256 + threadIdx.x;
  if (e < E) {
    int p = atomicAdd(&cursor[dst[e]], 1);
    es[p] = (unsigned int)src[e] | ((unsigned int)etype[e] << 16);  // src < 65536
  }
}

// ---- gather: FOUR nodes per wave (quarter-wave each, uint4 16B loads/lane).
// R3-proven structure: unconditional clamped load batches (predication and
// deeper unroll both measured slower), occ 6. deg<=16 fast path, overflow
// loop for deg>16 (Poisson-10: ~2.7%). Zero LDS.
__global__ __launch_bounds__(256, 6) void k_gather(
    const unsigned int* __restrict__ xb,
    _Float16* __restrict__ xrow0, _Float16* __restrict__ xrow1,
    const unsigned int* __restrict__ rel_pk,     // [R*D] this layer, packed
    const int* __restrict__ row_ptr, const unsigned int* __restrict__ es,
    const float2* __restrict__ q2, const int* __restrict__ h_index, int first) {
  int tid = threadIdx.x;
  int lane = tid & 63;
  int q = lane >> 4;                 // quarter: which of 4 nodes
  int lq = lane & 15;                // lane within quarter (dims 4lq..4lq+3)
  int w = (blockIdx.x * 256 + tid) >> 6;       // wave id in [0, N/4)
  int n = w * 4 + q;                 // node for this quarter
  int h0 = h_index[0], h1 = h_index[1];
  int rp = 0;
  if (lane < 5) rp = row_ptr[4 * w + lane];    // row_ptr[4w .. 4w+4]
  int rs = __shfl(rp, q);
  int re = __shfl(rp, q + 1);
  int deg = re - rs;
  int dc = min(deg, 16);
  unsigned int esv = 0;
  if (lq < dc) esv = es[rs + lq];              // quarter's edge list, one load
  float ax[4] = {0.f, 0.f, 0.f, 0.f};          // batch0, dims 4lq+0..3
  float ay[4] = {0.f, 0.f, 0.f, 0.f};          // batch1
  if (first) {
    // layer 0: x nonzero only at h0 (batch0) / h1 (batch1); loads only on match
    for (int j = 0; j < dc; ++j) {
      unsigned int pk = __shfl(esv, (q << 4) | j);
      int s = (int)(pk & 0xffffu), et = (int)(pk >> 16);
      if (s == h0 || s == h1) {
        uint4 xv = *(const uint4*)&xb[(size_t)s * D + 4 * lq];
        uint4 rv = *(const uint4*)&rel_pk[et * D + 4 * lq];
        float2 x0 = unpack_h2(xv.x), x1 = unpack_h2(xv.y),
               x2 = unpack_h2(xv.z), x3 = unpack_h2(xv.w);
        float2 r0 = unpack_h2(rv.x), r1 = unpack_h2(rv.y),
               r2 = unpack_h2(rv.z), r3 = unpack_h2(rv.w);
        if (s == h0) {
          ax[0] = fmaf(x0.x, r0.x, ax[0]); ax[1] = fmaf(x1.x, r1.x, ax[1]);
          ax[2] = fmaf(x2.x, r2.x, ax[2]); ax[3] = fmaf(x3.x, r3.x, ax[3]);
        }
        if (s == h1) {
          ay[0] = fmaf(x0.y, r0.y, ay[0]); ay[1] = fmaf(x1.y, r1.y, ay[1]);
          ay[2] = fmaf(x2.y, r2.y, ay[2]); ay[3] = fmaf(x3.y, r3.y, ay[3]);
        }
      }
    }
    for (int j = rs + 16; j < re; ++j) {       // overflow (rare)
      unsigned int pk = es[j];
      int s = (int)(pk & 0xffffu), et = (int)(pk >> 16);
      if (s == h0 || s == h1) {
        uint4 xv = *(const uint4*)&xb[(size_t)s * D + 4 * lq];
        uint4 rv = *(const uint4*)&rel_pk[et * D + 4 * lq];
        float2 x0 = unpack_h2(xv.x), x1 = unpack_h2(xv.y),
               x2 = unpack_h2(xv.z), x3 = unpack_h2(xv.w);
        float2 r0 = unpack_h2(rv.x), r1 = unpack_h2(rv.y),
               r2 = unpack_h2(rv.z), r3 = unpack_h2(rv.w);
        if (s == h0) {
          ax[0] = fmaf(x0.x, r0.x, ax[0]); ax[1] = fmaf(x1.x, r1.x, ax[1]);
          ax[2] = fmaf(x2.x, r2.x, ax[2]); ax[3] = fmaf(x3.x, r3.x, ax[3]);
        }
        if (s == h1) {
          ay[0] = fmaf(x0.y, r0.y, ay[0]); ay[1] = fmaf(x1.y, r1.y, ay[1]);
          ay[2] = fmaf(x2.y, r2.y, ay[2]); ay[3] = fmaf(x3.y, r3.y, ay[3]);
        }
      }
    }
  } else {
    int rounds = (dc + 3) >> 2;
    int r0q = __shfl(rounds, 0), r1q = __shfl(rounds, 16);
    int r2q = __shfl(rounds, 32), r3q = __shfl(rounds, 48);
    int maxr = max(max(r0q, r1q), max(r2q, r3q));   // wave-uniform bound
    for (int jr = 0; jr < maxr; ++jr) {
      int j = jr * 4;
      unsigned int pk[4];
      uint4 xv[4], rv[4];
      #pragma unroll
      for (int u = 0; u < 4; ++u) {
        int iu = max(min(j + u, dc - 1), 0);   // clamped (safe for done quarter)
        pk[u] = __shfl(esv, (q << 4) | iu);
      }
      #pragma unroll
      for (int u = 0; u < 4; ++u) {
        xv[u] = *(const uint4*)&xb[(size_t)(pk[u] & 0xffffu) * D + 4 * lq];
        rv[u] = *(const uint4*)&rel_pk[(pk[u] >> 16) * D + 4 * lq];
      }
      #pragma unroll
      for (int u = 0; u < 4; ++u) {
        if (j + u < dc) {
          float2 x0 = unpack_h2(xv[u].x), x1 = unpack_h2(xv[u].y),
                 x2 = unpack_h2(xv[u].z), x3 = unpack_h2(xv[u].w);
          float2 r0 = unpack_h2(rv[u].x), r1 = unpack_h2(rv[u].y),
                 r2 = unpack_h2(rv[u].z), r3 = unpack_h2(rv[u].w);
          ax[0] = fmaf(x0.x, r0.x, ax[0]); ay[0] = fmaf(x0.y, r0.y, ay[0]);
          ax[1] = fmaf(x1.x, r1.x, ax[1]); ay[1] = fmaf(x1.y, r1.y, ay[1]);
          ax[2] = fmaf(x2.x, r2.x, ax[2]); ay[2] = fmaf(x2.y, r2.y, ay[2]);
          ax[3] = fmaf(x3.x, r3.x, ax[3]); ay[3] = fmaf(x3.y, r3.y, ay[3]);
        }
      }
    }
    for (int j = rs + 16; j < re; ++j) {       // overflow (rare)
      unsigned int pk = es[j];
      uint4 xv = *(const uint4*)&xb[(size_t)(pk & 0xffffu) * D + 4 * lq];
      uint4 rv = *(const uint4*)&rel_pk[(pk >> 16) * D + 4 * lq];
      float2 x0 = unpack_h2(xv.x), x1 = unpack_h2(xv.y),
             x2 = unpack_h2(xv.z), x3 = unpack_h2(xv.w);
      float2 r0 = unpack_h2(rv.x), r1 = unpack_h2(rv.y),
             r2 = unpack_h2(rv.z), r3 = unpack_h2(rv.w);
      ax[0] = fmaf(x0.x, r0.x, ax[0]); ay[0] = fmaf(x0.y, r0.y, ay[0]);
      ax[1] = fmaf(x1.x, r1.x, ax[1]); ay[1] = fmaf(x1.y, r1.y, ay[1]);
      ax[2] = fmaf(x2.x, r2.x, ax[2]); ay[2] = fmaf(x2.y, r2.y, ay[2]);
      ax[3] = fmaf(x3.x, r3.x, ax[3]); ay[3] = fmaf(x3.y, r3.y, ay[3]);
    }
  }
  // + boundary (fp32): q2[d] = (batch0 val, batch1 val) of dim d
  if (n == h0) {
    const float4* qp = (const float4*)&q2[4 * lq];   // q2[4lq], q2[4lq+1]
    float4 qa = qp[0], qb = qp[1];
    ax[0] += qa.x; ax[1] += qa.z; ax[2] += qb.x; ax[3] += qb.z;
  }
  if (n == h1) {
    const float4* qp = (const float4*)&q2[4 * lq];
    float4 qa = qp[0], qb = qp[1];
    ay[0] += qa.y; ay[1] += qa.w; ay[2] += qb.y; ay[3] += qb.w;
  }
  uint2 st0, st1;
  st0.x = pack_h2(ax[0], ax[1]); st0.y = pack_h2(ax[2], ax[3]);
  st1.x = pack_h2(ay[0], ay[1]); st1.y = pack_h2(ay[2], ay[3]);
  *(uint2*)&xrow0[(size_t)n * 2 * D + D + 4 * lq] = st0;   // agg-half of A rows
  *(uint2*)&xrow1[(size_t)n * 2 * D + D + 4 * lq] = st1;
}

// ---- MFMA linear + LN + relu + shortcut ----
// One wave per 16-node tile, both batches. Zero LDS. Grid 2500 x 64.
// first=1: x-half A-frags + residual synthesized from qh (zero elsewhere)
// -> no 30.7MB zero-memset needed. f16-exact vs the old memset+init path.
__global__ __launch_bounds__(64) void k_linear(
    unsigned int* __restrict__ xb,
    _Float16* __restrict__ xrow0, _Float16* __restrict__ xrow1,
    const unsigned short* __restrict__ Wf,
    const float* __restrict__ lin_b, const float* __restrict__ ln_g,
    const float* __restrict__ ln_b, const _Float16* __restrict__ qh,
    const int* __restrict__ h_index, int layer, int first) {
  int lane = threadIdx.x;
  int nb = blockIdx.x * 16;
  int c = lane & 15, rg = lane >> 4;
  int h0 = h_index[0], h1 = h_index[1];
  // B-fragments (16 x 16 B, L2-hot)
  const v8h* wf = (const v8h*)(Wf + (size_t)layer * 8192);
  v8h Bf[4][4];
  #pragma unroll
  for (int ct = 0; ct < 4; ++ct)
    #pragma unroll
    for (int ks = 0; ks < 4; ++ks)
      Bf[ct][ks] = wf[(ct * 4 + ks) * 64 + lane];
  v4f acc0[4], acc1[4];
  #pragma unroll
  for (int ct = 0; ct < 4; ++ct) {
    acc0[ct] = (v4f){0.f, 0.f, 0.f, 0.f};
    acc1[ct] = (v4f){0.f, 0.f, 0.f, 0.f};
  }
  // K-loop: 4 k-steps x (2 A-loads + 8 MFMA)
  #pragma unroll
  for (int ks = 0; ks < 4; ++ks) {
    v8h A0, A1;
    if (first && ks < 2) {           // layer-0 x-half: qh rows at h0/h1, else 0
      int node = nb + c;
      A0 = (node == h0) ? *(const v8h*)(qh + ks * 32 + rg * 8) : zero8();
      A1 = (node == h1) ? *(const v8h*)(qh + D + ks * 32 + rg * 8) : zero8();
    } else {
      size_t aoff = (size_t)(nb + c) * 2 * D + ks * 32 + rg * 8;
      A0 = *(const v8h*)(xrow0 + aoff);
      A1 = *(const v8h*)(xrow1 + aoff);
    }
    #pragma unroll
    for (int ct = 0; ct < 4; ++ct) {
      acc0[ct] = __builtin_amdgcn_mfma_f32_16x16x32_f16(A0, Bf[ct][ks], acc0[ct], 0, 0, 0);
      acc1[ct] = __builtin_amdgcn_mfma_f32_16x16x32_f16(A1, Bf[ct][ks], acc1[ct], 0, 0, 0);
    }
  }
  // epilogue: +bias, LN over 64 outs (16-lane col-group x 4 ct), relu, +x
  float bias4[4], g4[4], be4[4];
  #pragma unroll
  for (int ct = 0; ct < 4; ++ct) {
    int d = ct * 16 + c;
    bias4[ct] = lin_b[layer * D + d];
    g4[ct]    = ln_g[layer * D + d];
    be4[ct]   = ln_b[layer * D + d];
  }
  #pragma unroll
  for (int j = 0; j < 4; ++j) {
    int node = nb + rg * 4 + j;
    float v0[4], v1[4];
    float s10 = 0.f, s20 = 0.f, s11 = 0.f, s21 = 0.f;
    #pragma unroll
    for (int ct = 0; ct < 4; ++ct) {
      v0[ct] = acc0[ct][j] + bias4[ct];
      v1[ct] = acc1[ct][j] + bias4[ct];
      s10 += v0[ct]; s20 += v0[ct] * v0[ct];
      s11 += v1[ct]; s21 += v1[ct] * v1[ct];
    }
    #pragma unroll
    for (int mk = 1; mk < 16; mk <<= 1) {   // reduce over the 16-lane col group
      s10 += __shfl_xor(s10, mk); s20 += __shfl_xor(s20, mk);
      s11 += __shfl_xor(s11, mk); s21 += __shfl_xor(s21, mk);
    }
    float mu0 = s10 * (1.f / D), var0 = s20 * (1.f / D) - mu0 * mu0;
    float mu1 = s11 * (1.f / D), var1 = s21 * (1.f / D) - mu1 * mu1;
    float rs0 = rsqrtf(var0 + EPS), rs1 = rsqrtf(var1 + EPS);
    #pragma unroll
    for (int ct = 0; ct < 4; ++ct) {
      int d = ct * 16 + c;
      float o0 = fmaxf((v0[ct] - mu0) * rs0 * g4[ct] + be4[ct], 0.f);
      float o1 = fmaxf((v1[ct] - mu1) * rs1 * g4[ct] + be4[ct], 0.f);
      float xr0, xr1;
      if (first) {                    // residual = f16 query at h0/h1, else 0
        xr0 = (node == h0) ? (float)qh[d] : 0.f;
        xr1 = (node == h1) ? (float)qh[D + d] : 0.f;
      } else {
        float2 xv = unpack_h2(xb[(size_t)node * D + d]);  // f16 residual
        xr0 = xv.x; xr1 = xv.y;
      }
      float r0 = o0 + xr0, r1 = o1 + xr1;
      xb[(size_t)node * D + d] = pack_h2(r0, r1);          // for gather / residual
      xrow0[(size_t)node * 2 * D + d] = (_Float16)r0;      // x-half for next linear/mlp
      xrow1[(size_t)node * 2 * D + d] = (_Float16)r1;
    }
  }
}

// ---- MFMA final MLP: relu([x, query] @ mlp_w + mlp_b) -> fp32 out ----
__global__ __launch_bounds__(64) void k_mlp(
    const _Float16* __restrict__ xrow0, const _Float16* __restrict__ xrow1,
    const _Float16* __restrict__ qh,            // [2][64] f16
    const unsigned short* __restrict__ Wm,      // 32 fragments
    const float* __restrict__ mlp_b,
    float* __restrict__ outf) {
  int lane = threadIdx.x;
  int nb = blockIdx.x * 16;
  int c = lane & 15, rg = lane >> 4;
  const v8h* wm = (const v8h*)Wm;
  v4f acc0[8], acc1[8];
  #pragma unroll
  for (int ct = 0; ct < 8; ++ct) {
    acc0[ct] = (v4f){0.f, 0.f, 0.f, 0.f};
    acc1[ct] = (v4f){0.f, 0.f, 0.f, 0.f};
  }
  #pragma unroll
  for (int ks = 0; ks < 4; ++ks) {
    v8h A0, A1;
    if (ks < 2) {                       // x half: k = ks*32 + rg*8 + j in [0,64)
      size_t aoff = (size_t)(nb + c) * 2 * D + ks * 32 + rg * 8;
      A0 = *(const v8h*)(xrow0 + aoff);
      A1 = *(const v8h*)(xrow1 + aoff);
    } else {                            // query half: node-invariant
      int qoff = (ks - 2) * 32 + rg * 8;
      A0 = *(const v8h*)(qh + qoff);
      A1 = *(const v8h*)(qh + D + qoff);
    }
    #pragma unroll
    for (int ct = 0; ct < 8; ++ct) {
      v8h Bv = wm[(ct * 4 + ks) * 64 + lane];
      acc0[ct] = __builtin_amdgcn_mfma_f32_16x16x32_f16(A0, Bv, acc0[ct], 0, 0, 0);
      acc1[ct] = __builtin_amdgcn_mfma_f32_16x16x32_f16(A1, Bv, acc1[ct], 0, 0, 0);
    }
  }
  // epilogue: +bias, relu, store. out flat = [2][N][128] fp32.
  #pragma unroll
  for (int ct = 0; ct < 8; ++ct) {
    int d = ct * 16 + c;
    float bias = mlp_b[d];
    #pragma unroll
    for (int j = 0; j < 4; ++j) {
      int node = nb + rg * 4 + j;
      outf[(size_t)node * 2 * D + d]       = fmaxf(acc0[ct][j] + bias, 0.f);
      outf[((size_t)N + node) * 2 * D + d] = fmaxf(acc1[ct][j] + bias, 0.f);
    }
  }
}

}  // namespace

extern "C" void kernel_launch(void* const* d_in, const int* in_sizes, int n_in,
                              void* d_out, int out_size, void* d_ws, size_t ws_size,
                              hipStream_t stream) {
  const float* rel_reps = (const float*)d_in[0];
  const int* h_index    = (const int*)d_in[1];
  const int* r_index    = (const int*)d_in[2];
  const int* edge_index = (const int*)d_in[3];
  const int* edge_type  = (const int*)d_in[4];
  const float* proj_w1  = (const float*)d_in[5];
  const float* proj_b1  = (const float*)d_in[6];
  const float* proj_w2  = (const float*)d_in[7];
  const float* proj_b2  = (const float*)d_in[8];
  const float* lin_w    = (const float*)d_in[9];
  const float* lin_b    = (const float*)d_in[10];
  const float* ln_g     = (const float*)d_in[11];
  const float* ln_b     = (const float*)d_in[12];
  const float* mlp_w    = (const float*)d_in[13];
  const float* mlp_b    = (const float*)d_in[14];

  // workspace: xb | xrow0 | xrow1 | rel_pk | Wf | Wm | qh | rel_all | query |
  //            cnt | row_ptr | cursor | es | bsum
  unsigned int* xb = (unsigned int*)d_ws;                  // N*D
  _Float16* xrow0 = (_Float16*)(xb + (size_t)N * D);       // N*128
  _Float16* xrow1 = xrow0 + (size_t)N * 2 * D;             // N*128
  unsigned int* rel_pk = (unsigned int*)(xrow1 + (size_t)N * 2 * D);  // L*R*D
  unsigned short* Wf = (unsigned short*)(rel_pk + (size_t)L * R * D); // L*8192
  unsigned short* Wm = Wf + (size_t)L * 8192;              // 16384
  _Float16* qh = (_Float16*)(Wm + 16384);                  // 128
  float* rel_all = (float*)(qh + 128);                     // 2*L*R*D
  float* query   = rel_all + (size_t)2 * L * R * D;        // 2*D
  int*   cnt     = (int*)(query + 2 * D);
  int*   row_ptr = cnt + N;
  int*   cursor  = row_ptr + (N + 1);
  unsigned int* es = (unsigned int*)(cursor + N);
  int*   bsum    = (int*)(es + E);

  const int* srcp = edge_index;
  const int* dstp = edge_index + E;

  // no big memset: layer-0 paths synthesize zero/query state directly
  hipMemsetAsync(cnt, 0, N * sizeof(int), stream);
  k_rel<<<L * B * R + 1, 64, 0, stream>>>(rel_reps, proj_w1, proj_b1, proj_w2, proj_b2,
                                          rel_all, h_index, r_index,
                                          xb, query, qh);
  k_pack<<<128, 256, 0, stream>>>((const float2*)rel_all, rel_pk, lin_w, Wf, mlp_w, Wm);
  k_hist<<<EB, 256, 0, stream>>>(dstp, cnt);
  k_scan1<<<NB, 256, 0, stream>>>(cnt, row_ptr, bsum);
  k_scan3<<<NB, 256, 0, stream>>>(row_ptr, bsum, cursor);
  k_fill<<<EB, 256, 0, stream>>>(srcp, dstp, edge_type, cursor, es);

  for (int l = 0; l < L; ++l) {
    k_gather<<<N / 16, 256, 0, stream>>>(xb, xrow0, xrow1,
                                         rel_pk + (size_t)l * R * D,
                                         row_ptr, es, (const float2*)query, h_index,
                                         (l == 0) ? 1 : 0);
    k_linear<<<N / 16, 64, 0, stream>>>(xb, xrow0, xrow1,
                                        Wf, lin_b, ln_g, ln_b, qh, h_index,
                                        l, (l == 0) ? 1 : 0);
  }
  k_mlp<<<N / 16, 64, 0, stream>>>(xrow0, xrow1, qh, Wm, mlp_b, (float*)d_out);
}

// Round 9
// 316.721 us; speedup vs baseline: 1.0527x; 1.0323x over previous
//
#include <hip/hip_runtime.h>
#include <hip/hip_bf16.h>

namespace {

constexpr int B = 2;
constexpr int N = 40000;
constexpr int E = 400000;
constexpr int R = 64;
constexpr int D = 64;
constexpr int L = 6;
constexpr float EPS = 1e-5f;
constexpr int NB = (N + 255) / 256;   // 157 node-grid blocks
constexpr int EB = (E + 255) / 256;   // 1563 edge-grid blocks

typedef _Float16 v8h __attribute__((ext_vector_type(8)));
typedef _Float16 v2h __attribute__((ext_vector_type(2)));
typedef float    v4f __attribute__((ext_vector_type(4)));

__device__ __forceinline__ unsigned int pack_h2(float a, float b) {
  v2h p; p.x = (_Float16)a; p.y = (_Float16)b;
  return __builtin_bit_cast(unsigned int, p);
}
__device__ __forceinline__ float2 unpack_h2(unsigned int u) {
  v2h p = __builtin_bit_cast(v2h, u);
  return make_float2((float)p.x, (float)p.y);
}

// Batch-interleaved packed element = (batch0, batch1) f16 in one dword.

// ---- relation projection MLP, BOTH batches per block, writes rel_pk
//      directly (packed). Weight loads shared across batches (2 fmaf/load).
//      Last block does init. ----
__global__ __launch_bounds__(64) void k_rel(
    const float* __restrict__ rel_reps,
    const float* __restrict__ pw1, const float* __restrict__ pb1,
    const float* __restrict__ pw2, const float* __restrict__ pb2,
    unsigned int* __restrict__ rel_pk,
    const int* __restrict__ h_index, const int* __restrict__ r_index,
    unsigned int* __restrict__ xb,
    _Float16* __restrict__ xrow0, _Float16* __restrict__ xrow1,
    float* __restrict__ query_f, _Float16* __restrict__ qh) {
  __shared__ float row0[D], row1[D], t0[D], t1[D];
  int idx = blockIdx.x;             // [0, L*R] — last block = init
  int d = threadIdx.x;
  if (idx == L * R) {               // ---- init block ----
    int h0 = h_index[0], h1 = h_index[1];
    float q0 = rel_reps[r_index[0] * D + d];
    float q1 = rel_reps[(R + r_index[1]) * D + d];
    query_f[d * 2] = q0; query_f[d * 2 + 1] = q1;
    qh[d]     = (_Float16)q0;
    qh[D + d] = (_Float16)q1;
    if (h0 == h1) {
      xb[(size_t)h0 * D + d] = pack_h2(q0, q1);
    } else {
      xb[(size_t)h0 * D + d] = pack_h2(q0, 0.f);
      xb[(size_t)h1 * D + d] = pack_h2(0.f, q1);
    }
    xrow0[(size_t)h0 * 2 * D + d] = (_Float16)q0;   // x-half of A rows
    xrow1[(size_t)h1 * 2 * D + d] = (_Float16)q1;
    return;
  }
  int l = idx / R, r = idx - l * R;
  row0[d] = rel_reps[(size_t)r * D + d];            // batch 0 row
  row1[d] = rel_reps[(size_t)(R + r) * D + d];      // batch 1 row
  __syncthreads();
  const float* w1 = pw1 + (size_t)l * D * D;
  float bb = pb1[l * D + d];
  float a0 = bb, a1 = bb;
  for (int k = 0; k < D; ++k) {
    float wv = w1[k * D + d];
    a0 = fmaf(row0[k], wv, a0);
    a1 = fmaf(row1[k], wv, a1);
  }
  t0[d] = fmaxf(a0, 0.f);
  t1[d] = fmaxf(a1, 0.f);
  __syncthreads();
  const float* w2 = pw2 + (size_t)l * D * D;
  float bb2 = pb2[l * D + d];
  float b0 = bb2, b1 = bb2;
  for (int k = 0; k < D; ++k) {
    float wv = w2[k * D + d];
    b0 = fmaf(t0[k], wv, b0);
    b1 = fmaf(t1[k], wv, b1);
  }
  rel_pk[((size_t)l * R + r) * D + d] = pack_h2(b0, b1);
}

// ---- pack kernel: lin_w (24 blocks) | mlp_w (8 blocks) ----
__global__ __launch_bounds__(256) void k_pack(
    const float* __restrict__ lin_w, unsigned short* __restrict__ Wf,
    const float* __restrict__ mlp_w, unsigned short* __restrict__ Wm) {
  int blk = blockIdx.x;
  int tid = threadIdx.x;
  if (blk < 24) {                    // lin_w: L*16 = 96 frag-groups, 4/block
    int idx = blk * 4 + (tid >> 6);
    int lane = tid & 63;
    int l = idx >> 4, ct = (idx >> 2) & 3, ks = idx & 3;
    int n = ct * 16 + (lane & 15);
    #pragma unroll
    for (int j = 0; j < 8; ++j) {
      int k = ks * 32 + (lane >> 4) * 8 + j;
      _Float16 v = (_Float16)lin_w[(size_t)l * 2 * D * D + (size_t)k * D + n];
      Wf[(size_t)l * 8192 + ((size_t)((ct * 4 + ks) * 64) + lane) * 8 + j] =
          __builtin_bit_cast(unsigned short, v);
    }
  } else {                           // mlp_w: 32 frag-groups, 4/block
    int idx = (blk - 24) * 4 + (tid >> 6);
    int lane = tid & 63;
    int ct = idx >> 2, ks = idx & 3;
    int n = ct * 16 + (lane & 15);
    #pragma unroll
    for (int j = 0; j < 8; ++j) {
      int k = ks * 32 + (lane >> 4) * 8 + j;
      _Float16 v = (_Float16)mlp_w[(size_t)k * 2 * D + n];
      Wm[((size_t)idx * 64 + lane) * 8 + j] = __builtin_bit_cast(unsigned short, v);
    }
  }
}

// ---- CSR build ----
__global__ __launch_bounds__(256) void k_hist(const int* __restrict__ dst,
                                              int* __restrict__ cnt) {
  int e = blockIdx.x * 256 + threadIdx.x;
  if (e < E) atomicAdd(&cnt[dst[e]], 1);
}

__global__ __launch_bounds__(256) void k_scan1(const int* __restrict__ cnt,
                                               int* __restrict__ row_ptr,
                                               int* __restrict__ bsum) {
  __shared__ int s[256];
  int t = threadIdx.x;
  int i = blockIdx.x * 256 + t;
  int v = (i < N) ? cnt[i] : 0;
  s[t] = v;
  __syncthreads();
  #pragma unroll
  for (int off = 1; off < 256; off <<= 1) {   // Hillis-Steele inclusive
    int u = (t >= off) ? s[t - off] : 0;
    __syncthreads();
    s[t] += u;
    __syncthreads();
  }
  if (i < N) row_ptr[i] = s[t] - v;           // exclusive-in-block
  if (t == 255) bsum[blockIdx.x] = s[255];
}

// scan3: add prefix of block sums (block-reduced in LDS) + init cursor.
__global__ __launch_bounds__(256) void k_scan3(int* __restrict__ row_ptr,
                                               const int* __restrict__ bsum,
                                               int* __restrict__ cursor) {
  __shared__ int red[256];
  int t = threadIdx.x;
  int v = (t < (int)blockIdx.x) ? bsum[t] : 0;   // blockIdx.x <= 156 < 256
  red[t] = v;
  __syncthreads();
  #pragma unroll
  for (int off = 128; off > 0; off >>= 1) {
    if (t < off) red[t] += red[t + off];
    __syncthreads();
  }
  int offv = red[0];
  int i = blockIdx.x * 256 + t;
  if (i < N) {
    int r = row_ptr[i] + offv;
    row_ptr[i] = r;
    cursor[i] = r;
  }
  if (i == N - 1) row_ptr[N] = E;
}

__global__ __launch_bounds__(256) void k_fill(const int* __restrict__ src,
                                              const int* __restrict__ dst,
                                              const int* __restrict__ etype,
                                              int* __restrict__ cursor,
                                              unsigned int* __restrict__ es) {
  int e = blockIdx.x * 256 + threadIdx.x;
  if (e < E) {
    int p = atomicAdd(&cursor[dst[e]], 1);
    es[p] = (unsigned int)src[e] | ((unsigned int)etype[e] << 16);  // src < 65536
  }
}

// ---- gather: FOUR nodes per wave (quarter-wave each, uint4 16B loads/lane).
// R3-proven structure: unconditional clamped load batches (predication,
// deeper unroll, and rel-LDS staging all measured slower/neutral), occ 6.
// deg<=16 fast path, overflow loop for deg>16 (Poisson-10: ~2.7%). Zero LDS.
__global__ __launch_bounds__(256, 6) void k_gather(
    const unsigned int* __restrict__ xb,
    _Float16* __restrict__ xrow0, _Float16* __restrict__ xrow1,
    const unsigned int* __restrict__ rel_pk,     // [R*D] this layer, packed
    const int* __restrict__ row_ptr, const unsigned int* __restrict__ es,
    const float2* __restrict__ q2, const int* __restrict__ h_index, int first) {
  int tid = threadIdx.x;
  int lane = tid & 63;
  int q = lane >> 4;                 // quarter: which of 4 nodes
  int lq = lane & 15;                // lane within quarter (dims 4lq..4lq+3)
  int w = (blockIdx.x * 256 + tid) >> 6;       // wave id in [0, N/4)
  int n = w * 4 + q;                 // node for this quarter
  int h0 = h_index[0], h1 = h_index[1];
  int rp = 0;
  if (lane < 5) rp = row_ptr[4 * w + lane];    // row_ptr[4w .. 4w+4]
  int rs = __shfl(rp, q);
  int re = __shfl(rp, q + 1);
  int deg = re - rs;
  int dc = min(deg, 16);
  unsigned int esv = 0;
  if (lq < dc) esv = es[rs + lq];              // quarter's edge list, one load
  float ax[4] = {0.f, 0.f, 0.f, 0.f};          // batch0, dims 4lq+0..3
  float ay[4] = {0.f, 0.f, 0.f, 0.f};          // batch1
  if (first) {
    // layer 0: x nonzero only at h0 (batch0) / h1 (batch1); loads only on match
    for (int j = 0; j < dc; ++j) {
      unsigned int pk = __shfl(esv, (q << 4) | j);
      int s = (int)(pk & 0xffffu), et = (int)(pk >> 16);
      if (s == h0 || s == h1) {
        uint4 xv = *(const uint4*)&xb[(size_t)s * D + 4 * lq];
        uint4 rv = *(const uint4*)&rel_pk[et * D + 4 * lq];
        float2 x0 = unpack_h2(xv.x), x1 = unpack_h2(xv.y),
               x2 = unpack_h2(xv.z), x3 = unpack_h2(xv.w);
        float2 r0 = unpack_h2(rv.x), r1 = unpack_h2(rv.y),
               r2 = unpack_h2(rv.z), r3 = unpack_h2(rv.w);
        if (s == h0) {
          ax[0] = fmaf(x0.x, r0.x, ax[0]); ax[1] = fmaf(x1.x, r1.x, ax[1]);
          ax[2] = fmaf(x2.x, r2.x, ax[2]); ax[3] = fmaf(x3.x, r3.x, ax[3]);
        }
        if (s == h1) {
          ay[0] = fmaf(x0.y, r0.y, ay[0]); ay[1] = fmaf(x1.y, r1.y, ay[1]);
          ay[2] = fmaf(x2.y, r2.y, ay[2]); ay[3] = fmaf(x3.y, r3.y, ay[3]);
        }
      }
    }
    for (int j = rs + 16; j < re; ++j) {       // overflow (rare)
      unsigned int pk = es[j];
      int s = (int)(pk & 0xffffu), et = (int)(pk >> 16);
      if (s == h0 || s == h1) {
        uint4 xv = *(const uint4*)&xb[(size_t)s * D + 4 * lq];
        uint4 rv = *(const uint4*)&rel_pk[et * D + 4 * lq];
        float2 x0 = unpack_h2(xv.x), x1 = unpack_h2(xv.y),
               x2 = unpack_h2(xv.z), x3 = unpack_h2(xv.w);
        float2 r0 = unpack_h2(rv.x), r1 = unpack_h2(rv.y),
               r2 = unpack_h2(rv.z), r3 = unpack_h2(rv.w);
        if (s == h0) {
          ax[0] = fmaf(x0.x, r0.x, ax[0]); ax[1] = fmaf(x1.x, r1.x, ax[1]);
          ax[2] = fmaf(x2.x, r2.x, ax[2]); ax[3] = fmaf(x3.x, r3.x, ax[3]);
        }
        if (s == h1) {
          ay[0] = fmaf(x0.y, r0.y, ay[0]); ay[1] = fmaf(x1.y, r1.y, ay[1]);
          ay[2] = fmaf(x2.y, r2.y, ay[2]); ay[3] = fmaf(x3.y, r3.y, ay[3]);
        }
      }
    }
  } else {
    int rounds = (dc + 3) >> 2;
    int r0q = __shfl(rounds, 0), r1q = __shfl(rounds, 16);
    int r2q = __shfl(rounds, 32), r3q = __shfl(rounds, 48);
    int maxr = max(max(r0q, r1q), max(r2q, r3q));   // wave-uniform bound
    for (int jr = 0; jr < maxr; ++jr) {
      int j = jr * 4;
      unsigned int pk[4];
      uint4 xv[4], rv[4];
      #pragma unroll
      for (int u = 0; u < 4; ++u) {
        int iu = max(min(j + u, dc - 1), 0);   // clamped (safe for done quarter)
        pk[u] = __shfl(esv, (q << 4) | iu);
      }
      #pragma unroll
      for (int u = 0; u < 4; ++u) {
        xv[u] = *(const uint4*)&xb[(size_t)(pk[u] & 0xffffu) * D + 4 * lq];
        rv[u] = *(const uint4*)&rel_pk[(pk[u] >> 16) * D + 4 * lq];
      }
      #pragma unroll
      for (int u = 0; u < 4; ++u) {
        if (j + u < dc) {
          float2 x0 = unpack_h2(xv[u].x), x1 = unpack_h2(xv[u].y),
                 x2 = unpack_h2(xv[u].z), x3 = unpack_h2(xv[u].w);
          float2 r0 = unpack_h2(rv[u].x), r1 = unpack_h2(rv[u].y),
                 r2 = unpack_h2(rv[u].z), r3 = unpack_h2(rv[u].w);
          ax[0] = fmaf(x0.x, r0.x, ax[0]); ay[0] = fmaf(x0.y, r0.y, ay[0]);
          ax[1] = fmaf(x1.x, r1.x, ax[1]); ay[1] = fmaf(x1.y, r1.y, ay[1]);
          ax[2] = fmaf(x2.x, r2.x, ax[2]); ay[2] = fmaf(x2.y, r2.y, ay[2]);
          ax[3] = fmaf(x3.x, r3.x, ax[3]); ay[3] = fmaf(x3.y, r3.y, ay[3]);
        }
      }
    }
    for (int j = rs + 16; j < re; ++j) {       // overflow (rare)
      unsigned int pk = es[j];
      uint4 xv = *(const uint4*)&xb[(size_t)(pk & 0xffffu) * D + 4 * lq];
      uint4 rv = *(const uint4*)&rel_pk[(pk >> 16) * D + 4 * lq];
      float2 x0 = unpack_h2(xv.x), x1 = unpack_h2(xv.y),
             x2 = unpack_h2(xv.z), x3 = unpack_h2(xv.w);
      float2 r0 = unpack_h2(rv.x), r1 = unpack_h2(rv.y),
             r2 = unpack_h2(rv.z), r3 = unpack_h2(rv.w);
      ax[0] = fmaf(x0.x, r0.x, ax[0]); ay[0] = fmaf(x0.y, r0.y, ay[0]);
      ax[1] = fmaf(x1.x, r1.x, ax[1]); ay[1] = fmaf(x1.y, r1.y, ay[1]);
      ax[2] = fmaf(x2.x, r2.x, ax[2]); ay[2] = fmaf(x2.y, r2.y, ay[2]);
      ax[3] = fmaf(x3.x, r3.x, ax[3]); ay[3] = fmaf(x3.y, r3.y, ay[3]);
    }
  }
  // + boundary (fp32): q2[d] = (batch0 val, batch1 val) of dim d
  if (n == h0) {
    const float4* qp = (const float4*)&q2[4 * lq];   // q2[4lq], q2[4lq+1]
    float4 qa = qp[0], qb = qp[1];
    ax[0] += qa.x; ax[1] += qa.z; ax[2] += qb.x; ax[3] += qb.z;
  }
  if (n == h1) {
    const float4* qp = (const float4*)&q2[4 * lq];
    float4 qa = qp[0], qb = qp[1];
    ay[0] += qa.y; ay[1] += qa.w; ay[2] += qb.y; ay[3] += qb.w;
  }
  uint2 st0, st1;
  st0.x = pack_h2(ax[0], ax[1]); st0.y = pack_h2(ax[2], ax[3]);
  st1.x = pack_h2(ay[0], ay[1]); st1.y = pack_h2(ay[2], ay[3]);
  *(uint2*)&xrow0[(size_t)n * 2 * D + D + 4 * lq] = st0;   // agg-half of A rows
  *(uint2*)&xrow1[(size_t)n * 2 * D + D + 4 * lq] = st1;
}

// ---- MFMA linear + LN + relu + shortcut ----
// One wave per 16-node tile, both batches. Zero LDS. Grid 2500 x 64.
// Residual read from xb (f16) — no fp32 x buffer.
__global__ __launch_bounds__(64) void k_linear(
    unsigned int* __restrict__ xb,
    _Float16* __restrict__ xrow0, _Float16* __restrict__ xrow1,
    const unsigned short* __restrict__ Wf,
    const float* __restrict__ lin_b, const float* __restrict__ ln_g,
    const float* __restrict__ ln_b, int layer) {
  int lane = threadIdx.x;
  int nb = blockIdx.x * 16;
  int c = lane & 15, rg = lane >> 4;
  // B-fragments (16 x 16 B, L2-hot)
  const v8h* wf = (const v8h*)(Wf + (size_t)layer * 8192);
  v8h Bf[4][4];
  #pragma unroll
  for (int ct = 0; ct < 4; ++ct)
    #pragma unroll
    for (int ks = 0; ks < 4; ++ks)
      Bf[ct][ks] = wf[(ct * 4 + ks) * 64 + lane];
  v4f acc0[4], acc1[4];
  #pragma unroll
  for (int ct = 0; ct < 4; ++ct) {
    acc0[ct] = (v4f){0.f, 0.f, 0.f, 0.f};
    acc1[ct] = (v4f){0.f, 0.f, 0.f, 0.f};
  }
  // K-loop: 4 k-steps x (2 A-loads + 8 MFMA)
  #pragma unroll
  for (int ks = 0; ks < 4; ++ks) {
    size_t aoff = (size_t)(nb + c) * 2 * D + ks * 32 + rg * 8;
    v8h A0 = *(const v8h*)(xrow0 + aoff);
    v8h A1 = *(const v8h*)(xrow1 + aoff);
    #pragma unroll
    for (int ct = 0; ct < 4; ++ct) {
      acc0[ct] = __builtin_amdgcn_mfma_f32_16x16x32_f16(A0, Bf[ct][ks], acc0[ct], 0, 0, 0);
      acc1[ct] = __builtin_amdgcn_mfma_f32_16x16x32_f16(A1, Bf[ct][ks], acc1[ct], 0, 0, 0);
    }
  }
  // epilogue: +bias, LN over 64 outs (16-lane col-group x 4 ct), relu, +x
  float bias4[4], g4[4], be4[4];
  #pragma unroll
  for (int ct = 0; ct < 4; ++ct) {
    int d = ct * 16 + c;
    bias4[ct] = lin_b[layer * D + d];
    g4[ct]    = ln_g[layer * D + d];
    be4[ct]   = ln_b[layer * D + d];
  }
  #pragma unroll
  for (int j = 0; j < 4; ++j) {
    int node = nb + rg * 4 + j;
    float v0[4], v1[4];
    float s10 = 0.f, s20 = 0.f, s11 = 0.f, s21 = 0.f;
    #pragma unroll
    for (int ct = 0; ct < 4; ++ct) {
      v0[ct] = acc0[ct][j] + bias4[ct];
      v1[ct] = acc1[ct][j] + bias4[ct];
      s10 += v0[ct]; s20 += v0[ct] * v0[ct];
      s11 += v1[ct]; s21 += v1[ct] * v1[ct];
    }
    #pragma unroll
    for (int mk = 1; mk < 16; mk <<= 1) {   // reduce over the 16-lane col group
      s10 += __shfl_xor(s10, mk); s20 += __shfl_xor(s20, mk);
      s11 += __shfl_xor(s11, mk); s21 += __shfl_xor(s21, mk);
    }
    float mu0 = s10 * (1.f / D), var0 = s20 * (1.f / D) - mu0 * mu0;
    float mu1 = s11 * (1.f / D), var1 = s21 * (1.f / D) - mu1 * mu1;
    float rs0 = rsqrtf(var0 + EPS), rs1 = rsqrtf(var1 + EPS);
    #pragma unroll
    for (int ct = 0; ct < 4; ++ct) {
      int d = ct * 16 + c;
      float o0 = fmaxf((v0[ct] - mu0) * rs0 * g4[ct] + be4[ct], 0.f);
      float o1 = fmaxf((v1[ct] - mu1) * rs1 * g4[ct] + be4[ct], 0.f);
      float2 xv = unpack_h2(xb[(size_t)node * D + d]);    // f16 residual
      float r0 = o0 + xv.x, r1 = o1 + xv.y;
      xb[(size_t)node * D + d] = pack_h2(r0, r1);          // for gather / residual
      xrow0[(size_t)node * 2 * D + d] = (_Float16)r0;      // x-half for next linear/mlp
      xrow1[(size_t)node * 2 * D + d] = (_Float16)r1;
    }
  }
}

// ---- MFMA final MLP: relu([x, query] @ mlp_w + mlp_b) -> fp32 out ----
__global__ __launch_bounds__(64) void k_mlp(
    const _Float16* __restrict__ xrow0, const _Float16* __restrict__ xrow1,
    const _Float16* __restrict__ qh,            // [2][64] f16
    const unsigned short* __restrict__ Wm,      // 32 fragments
    const float* __restrict__ mlp_b,
    float* __restrict__ outf) {
  int lane = threadIdx.x;
  int nb = blockIdx.x * 16;
  int c = lane & 15, rg = lane >> 4;
  const v8h* wm = (const v8h*)Wm;
  v4f acc0[8], acc1[8];
  #pragma unroll
  for (int ct = 0; ct < 8; ++ct) {
    acc0[ct] = (v4f){0.f, 0.f, 0.f, 0.f};
    acc1[ct] = (v4f){0.f, 0.f, 0.f, 0.f};
  }
  #pragma unroll
  for (int ks = 0; ks < 4; ++ks) {
    v8h A0, A1;
    if (ks < 2) {                       // x half: k = ks*32 + rg*8 + j in [0,64)
      size_t aoff = (size_t)(nb + c) * 2 * D + ks * 32 + rg * 8;
      A0 = *(const v8h*)(xrow0 + aoff);
      A1 = *(const v8h*)(xrow1 + aoff);
    } else {                            // query half: node-invariant
      int qoff = (ks - 2) * 32 + rg * 8;
      A0 = *(const v8h*)(qh + qoff);
      A1 = *(const v8h*)(qh + D + qoff);
    }
    #pragma unroll
    for (int ct = 0; ct < 8; ++ct) {
      v8h Bv = wm[(ct * 4 + ks) * 64 + lane];
      acc0[ct] = __builtin_amdgcn_mfma_f32_16x16x32_f16(A0, Bv, acc0[ct], 0, 0, 0);
      acc1[ct] = __builtin_amdgcn_mfma_f32_16x16x32_f16(A1, Bv, acc1[ct], 0, 0, 0);
    }
  }
  // epilogue: +bias, relu, store. out flat = [2][N][128] fp32.
  #pragma unroll
  for (int ct = 0; ct < 8; ++ct) {
    int d = ct * 16 + c;
    float bias = mlp_b[d];
    #pragma unroll
    for (int j = 0; j < 4; ++j) {
      int node = nb + rg * 4 + j;
      outf[(size_t)node * 2 * D + d]       = fmaxf(acc0[ct][j] + bias, 0.f);
      outf[((size_t)N + node) * 2 * D + d] = fmaxf(acc1[ct][j] + bias, 0.f);
    }
  }
}

}  // namespace

extern "C" void kernel_launch(void* const* d_in, const int* in_sizes, int n_in,
                              void* d_out, int out_size, void* d_ws, size_t ws_size,
                              hipStream_t stream) {
  const float* rel_reps = (const float*)d_in[0];
  const int* h_index    = (const int*)d_in[1];
  const int* r_index    = (const int*)d_in[2];
  const int* edge_index = (const int*)d_in[3];
  const int* edge_type  = (const int*)d_in[4];
  const float* proj_w1  = (const float*)d_in[5];
  const float* proj_b1  = (const float*)d_in[6];
  const float* proj_w2  = (const float*)d_in[7];
  const float* proj_b2  = (const float*)d_in[8];
  const float* lin_w    = (const float*)d_in[9];
  const float* lin_b    = (const float*)d_in[10];
  const float* ln_g     = (const float*)d_in[11];
  const float* ln_b     = (const float*)d_in[12];
  const float* mlp_w    = (const float*)d_in[13];
  const float* mlp_b    = (const float*)d_in[14];

  // workspace: xb | xrow0 | xrow1 (one contiguous zero region, 30.7 MB) |
  //            rel_pk | Wf | Wm | qh | query | cnt | row_ptr | cursor |
  //            es | bsum    (big 16B-aligned arrays first)
  unsigned int* xb = (unsigned int*)d_ws;                  // N*D
  _Float16* xrow0 = (_Float16*)(xb + (size_t)N * D);       // N*128
  _Float16* xrow1 = xrow0 + (size_t)N * 2 * D;             // N*128
  unsigned int* rel_pk = (unsigned int*)(xrow1 + (size_t)N * 2 * D);  // L*R*D
  unsigned short* Wf = (unsigned short*)(rel_pk + (size_t)L * R * D); // L*8192
  unsigned short* Wm = Wf + (size_t)L * 8192;              // 16384
  _Float16* qh = (_Float16*)(Wm + 16384);                  // 128
  float* query   = (float*)(qh + 128);                     // 2*D
  int*   cnt     = (int*)(query + 2 * D);
  int*   row_ptr = cnt + N;
  int*   cursor  = row_ptr + (N + 1);
  unsigned int* es = (unsigned int*)(cursor + N);
  int*   bsum    = (int*)(es + E);

  const int* srcp = edge_index;
  const int* dstp = edge_index + E;

  // one memset covers xb + xrow0 + xrow1 (contiguous)
  hipMemsetAsync(xb, 0, (size_t)N * D * 4 + (size_t)N * 2 * D * 2 * 2, stream);
  hipMemsetAsync(cnt, 0, N * sizeof(int), stream);
  k_rel<<<L * R + 1, 64, 0, stream>>>(rel_reps, proj_w1, proj_b1, proj_w2, proj_b2,
                                      rel_pk, h_index, r_index,
                                      xb, xrow0, xrow1, query, qh);
  k_pack<<<32, 256, 0, stream>>>(lin_w, Wf, mlp_w, Wm);
  k_hist<<<EB, 256, 0, stream>>>(dstp, cnt);
  k_scan1<<<NB, 256, 0, stream>>>(cnt, row_ptr, bsum);
  k_scan3<<<NB, 256, 0, stream>>>(row_ptr, bsum, cursor);
  k_fill<<<EB, 256, 0, stream>>>(srcp, dstp, edge_type, cursor, es);

  for (int l = 0; l < L; ++l) {
    k_gather<<<N / 16, 256, 0, stream>>>(xb, xrow0, xrow1,
                                         rel_pk + (size_t)l * R * D,
                                         row_ptr, es, (const float2*)query, h_index,
                                         (l == 0) ? 1 : 0);
    k_linear<<<N / 16, 64, 0, stream>>>(xb, xrow0, xrow1,
                                        Wf, lin_b, ln_g, ln_b, l);
  }
  k_mlp<<<N / 16, 64, 0, stream>>>(xrow0, xrow1, qh, Wm, mlp_b, (float*)d_out);
}